// Round 6
// baseline (700.212 us; speedup 1.0000x reference)
//
#include <hip/hip_runtime.h>
#include <math.h>

#define IMG 112
#define CDIM 128
#define NTOK 49

// ================= K1: qkv = roll(x,-3,-3) @ w_qkv + b_qkv =================
// 128x128 tile, 256 threads, 8x8 micro (2x2 groups of 4x4 at offsets {0,64}).
// 1D grid, jc-FAST decode: the 3 tensor-blocks of one m-panel are adjacent in
// dispatch -> concurrent -> x panel fetched from HBM once (round 2's 2D grid
// serialized the jc sweep = 3x x refetch). NO register prefetch / pointer
// arrays (rounds 3/4 proved that spills acc[8][8] to scratch: +2.1 GB traffic).
// At padded to 133 (bank = (c4*5+r)%32, 2-way max = free; 132 was 4-way).
// Output layout: qkv[((b*16+wi)*16+wj)*49 + ph*7+pw][0:384], q/k pre-scaled.
__global__ __launch_bounds__(256, 4) void qkv_gemm_kernel(
    const float* __restrict__ x, const float* __restrict__ w,
    const float* __restrict__ bqkv, float* __restrict__ qkv)
{
    __shared__ float At[32][133];   // At[k][r] (A transposed), +1 pad vs 132
    __shared__ float Bs[32][132];   // Bs[k][j]
    const int tid = threadIdx.x;
    const int bid = blockIdx.x;
    const int panel = bid / 3;
    const int jc = bid - panel * 3;        // fast-varying: 0,1,2 adjacent
    const int m0 = panel << 7;
    const int j0 = jc << 7;
    const int tm = tid >> 4, tn = tid & 15;
    const float fscale = (jc < 2) ? 0.17677669529663687f : 1.0f;

    // hoisted A-load offsets: 4 ints only (+4 VGPR, no spill risk)
    const int c4A = (tid & 7) << 2;
    const int r0 = tid >> 3;               // 0..31
    int aoff[4];
#pragma unroll
    for (int i = 0; i < 4; i++) {
        int r = r0 + (i << 5);
        int m = m0 + r;
        int b = m / (IMG * IMG);
        int rem = m - b * (IMG * IMG);
        int hh = rem / IMG;
        int ww_ = rem - hh * IMG;
        int hs = hh + 3; if (hs >= IMG) hs -= IMG;   // roll(-3) fold
        int ws = ww_ + 3; if (ws >= IMG) ws -= IMG;
        aoff[i] = ((b * IMG + hs) * IMG + ws) * CDIM + c4A;
    }

    float acc[8][8];
#pragma unroll
    for (int i = 0; i < 8; i++)
#pragma unroll
        for (int j = 0; j < 8; j++) acc[i][j] = 0.0f;

    for (int kc = 0; kc < 4; kc++) {
        if (kc) __syncthreads();
        // A chunk: 128 rows x 32 k, stored transposed
#pragma unroll
        for (int i = 0; i < 4; i++) {
            float4 v = *(const float4*)(x + aoff[i] + (kc << 5));
            int r = r0 + (i << 5);
            At[c4A + 0][r] = v.x;
            At[c4A + 1][r] = v.y;
            At[c4A + 2][r] = v.z;
            At[c4A + 3][r] = v.w;
        }
        // B chunk: 32 k x 128 j
#pragma unroll
        for (int i = 0; i < 4; i++) {
            int idx = tid + (i << 8);
            int c = idx >> 5;
            int j4 = (idx & 31) << 2;
            *(float4*)(&Bs[c][j4]) = *(const float4*)(w + (size_t)((kc << 5) + c) * 384 + j0 + j4);
        }
        __syncthreads();
#pragma unroll
        for (int c = 0; c < 32; c++) {
            float4 a0 = *(const float4*)(&At[c][tm << 2]);
            float4 a1 = *(const float4*)(&At[c][64 + (tm << 2)]);
            float4 b0 = *(const float4*)(&Bs[c][tn << 2]);
            float4 b1 = *(const float4*)(&Bs[c][64 + (tn << 2)]);
            float av[8] = {a0.x, a0.y, a0.z, a0.w, a1.x, a1.y, a1.z, a1.w};
            float bv[8] = {b0.x, b0.y, b0.z, b0.w, b1.x, b1.y, b1.z, b1.w};
#pragma unroll
            for (int ii = 0; ii < 8; ii++)
#pragma unroll
                for (int jj = 0; jj < 8; jj++) acc[ii][jj] = fmaf(av[ii], bv[jj], acc[ii][jj]);
        }
    }
    const int jb0 = j0 + (tn << 2);
    float4 bq0 = *(const float4*)(bqkv + jb0);
    float4 bq1 = *(const float4*)(bqkv + jb0 + 64);
#pragma unroll
    for (int ih = 0; ih < 2; ih++) {
#pragma unroll
        for (int ii = 0; ii < 4; ii++) {
            int r = (ih << 6) + (tm << 2) + ii;
            int m = m0 + r;
            int b = m / (IMG * IMG);
            int rem = m - b * (IMG * IMG);
            int hh = rem / IMG;
            int ww_ = rem - hh * IMG;
            int wi = hh / 7, ph = hh - wi * 7;
            int wj = ww_ / 7, pw = ww_ - wj * 7;
            size_t mp = (size_t)(((b * 16 + wi) * 16 + wj) * 49 + ph * 7 + pw);
            int ai = (ih << 2) + ii;
            float4 o0, o1;
            o0.x = (acc[ai][0] + bq0.x) * fscale;
            o0.y = (acc[ai][1] + bq0.y) * fscale;
            o0.z = (acc[ai][2] + bq0.z) * fscale;
            o0.w = (acc[ai][3] + bq0.w) * fscale;
            o1.x = (acc[ai][4] + bq1.x) * fscale;
            o1.y = (acc[ai][5] + bq1.y) * fscale;
            o1.z = (acc[ai][6] + bq1.z) * fscale;
            o1.w = (acc[ai][7] + bq1.w) * fscale;
            *(float4*)(qkv + mp * 384 + jb0) = o0;
            *(float4*)(qkv + mp * 384 + jb0 + 64) = o1;
        }
    }
}

// ================= K2: wave-per-head window attention + fused proj =================
// (unchanged from round 5 — proven 688-total variant)
// LDS (floats):
//   QK/PV phase : [0,12544) k/v slabs (head h at h*3136: k 49x32 swz, v +1568)
//                 [12544,13220) bias table copy (169x4)
//   proj phase  : [0,6272) out tile 49x128 swz (aliases dead k/v)
// w_proj read directly from global (L2-resident broadcast), 3 barriers/block.
#define KVSLAB 3136
#define OFF_BT 12544
#define SM_FLOATS 13220

__global__ __launch_bounds__(256, 3) void attn_kernel(
    const float* __restrict__ qkv, const float* __restrict__ wproj,
    const float* __restrict__ bproj, const float* __restrict__ lsig,
    const float* __restrict__ btab, float* __restrict__ out)
{
    __shared__ float sm[SM_FLOATS];
    const int tid = threadIdx.x;
    const int lane = tid & 63;
    const int h = tid >> 6;
    const int bx = blockIdx.x;
    const int wi = (bx >> 4) & 15;
    const int wj = bx & 15;

    float* kh  = sm + h * KVSLAB;
    float* vh  = kh + 1568;
    float* bts = sm + OFF_BT;
    float* osb = sm;            // proj-phase alias

    for (int i = tid; i < 676; i += 256) bts[i] = btab[i];

    const bool fi = (wi == 15), fj = (wj == 15);
    float4 q[8];
    float qsq = 0.0f, ks = 0.0f;
    int pbit = 0, qbit = 0, rbase = 0;

    const float* blkbase = qkv + (size_t)bx * (49 * 384);

    if (lane < NTOK) {
        int nh_ = lane / 7, nw_ = lane - (lane / 7) * 7;
        rbase = (nh_ * 13 + nw_) * 4 + h;
        pbit = (nh_ < 4) ? 1 : 0;
        qbit = (nw_ < 4) ? 1 : 0;
        const float* rowp = blkbase + lane * 384 + h * 32;
#pragma unroll
        for (int d4 = 0; d4 < 8; d4++) {
            float4 qv = *(const float4*)(rowp + (d4 << 2));
            q[d4] = qv;
            qsq = fmaf(qv.x, qv.x, qsq); qsq = fmaf(qv.y, qv.y, qsq);
            qsq = fmaf(qv.z, qv.z, qsq); qsq = fmaf(qv.w, qv.w, qsq);
            float4 kv = *(const float4*)(rowp + 128 + (d4 << 2));
            ks = fmaf(kv.x, kv.x, ks); ks = fmaf(kv.y, kv.y, ks);
            ks = fmaf(kv.z, kv.z, ks); ks = fmaf(kv.w, kv.w, ks);
            *(float4*)(kh + lane * 32 + ((d4 ^ (lane & 7)) << 2)) = kv;
            float4 vv = *(const float4*)(rowp + 256 + (d4 << 2));
            *(float4*)(vh + lane * 32 + ((d4 ^ (lane & 7)) << 2)) = vv;
        }
    }
    __syncthreads();

    float4 o[8];
#pragma unroll
    for (int d4 = 0; d4 < 8; d4++) { o[d4].x = 0.f; o[d4].y = 0.f; o[d4].z = 0.f; o[d4].w = 0.f; }
    float inv = 0.0f;

    if (lane < NTOK) {
        const float coef = -0.5f * __expf(-2.0f * lsig[h]);
        float s[49];
#pragma unroll
        for (int m = 0; m < 49; m++) {
            const int mh = m / 7, mw = m - (m / 7) * 7;
            float qk = 0.0f;
#pragma unroll
            for (int d4 = 0; d4 < 8; d4++) {
                float4 k4 = *(const float4*)(kh + m * 32 + ((d4 ^ (m & 7)) << 2));
                qk = fmaf(q[d4].x, k4.x, qk); qk = fmaf(q[d4].y, k4.y, qk);
                qk = fmaf(q[d4].z, k4.z, qk); qk = fmaf(q[d4].w, k4.w, qk);
            }
            float ksm = __shfl(ks, m, 64);
            float dist = fmaxf(qsq + ksm - 2.0f * qk, 1e-12f);
            float bias = bts[rbase + ((6 - mh) * 13 + (6 - mw)) * 4];
            int msk = (fi ? (pbit ^ ((mh < 4) ? 1 : 0)) : 0) | (fj ? (qbit ^ ((mw < 4) ? 1 : 0)) : 0);
            s[m] = fmaf(coef, dist, msk ? bias - 100.0f : bias);
        }
        // register-resident softmax
        float mx = s[0];
#pragma unroll
        for (int m = 1; m < 49; m++) mx = fmaxf(mx, s[m]);
        float sum = 0.0f;
#pragma unroll
        for (int m = 0; m < 49; m++) { float e = __expf(s[m] - mx); s[m] = e; sum += e; }
        inv = 1.0f / sum;
#pragma unroll
        for (int m = 0; m < 49; m++) {
            const float p = s[m];
#pragma unroll
            for (int d4 = 0; d4 < 8; d4++) {
                float4 v4 = *(const float4*)(vh + m * 32 + ((d4 ^ (m & 7)) << 2));
                o[d4].x = fmaf(p, v4.x, o[d4].x);
                o[d4].y = fmaf(p, v4.y, o[d4].y);
                o[d4].z = fmaf(p, v4.z, o[d4].z);
                o[d4].w = fmaf(p, v4.w, o[d4].w);
            }
        }
    }
    __syncthreads();   // all waves done reading k/v -> safe to alias

    if (lane < NTOK) {
#pragma unroll
        for (int d4 = 0; d4 < 8; d4++) {
            float4 ov;
            ov.x = o[d4].x * inv; ov.y = o[d4].y * inv;
            ov.z = o[d4].z * inv; ov.w = o[d4].w * inv;
            int gg = (h << 3) + d4;
            *(float4*)(osb + lane * 128 + ((gg ^ (lane & 7)) << 2)) = ov;
        }
    }
    __syncthreads();

    // ---- fused proj: out_tile(49x128) @ w_proj(128x128) + b_proj ----
    const int e4 = tid & 31;
    const int rowbase = tid >> 5;
    float4 bv = *(const float4*)(bproj + (e4 << 2));
    float4 pacc[7];
#pragma unroll
    for (int r = 0; r < 7; r++) pacc[r] = bv;

#pragma unroll 4
    for (int c = 0; c < 32; c++) {
        const float* wr = wproj + ((c << 2) * 128) + (e4 << 2);
        float4 w0 = *(const float4*)(wr);
        float4 w1 = *(const float4*)(wr + 128);
        float4 w2 = *(const float4*)(wr + 256);
        float4 w3 = *(const float4*)(wr + 384);
#pragma unroll
        for (int r = 0; r < 7; r++) {
            int nn = rowbase + (r << 3);
            if (nn < NTOK) {
                float4 o4 = *(const float4*)(osb + nn * 128 + ((c ^ (nn & 7)) << 2));
                float4 a = pacc[r];
                a.x = fmaf(o4.x, w0.x, a.x); a.y = fmaf(o4.x, w0.y, a.y);
                a.z = fmaf(o4.x, w0.z, a.z); a.w = fmaf(o4.x, w0.w, a.w);
                a.x = fmaf(o4.y, w1.x, a.x); a.y = fmaf(o4.y, w1.y, a.y);
                a.z = fmaf(o4.y, w1.z, a.z); a.w = fmaf(o4.y, w1.w, a.w);
                a.x = fmaf(o4.z, w2.x, a.x); a.y = fmaf(o4.z, w2.y, a.y);
                a.z = fmaf(o4.z, w2.z, a.z); a.w = fmaf(o4.z, w2.w, a.w);
                a.x = fmaf(o4.w, w3.x, a.x); a.y = fmaf(o4.w, w3.y, a.y);
                a.z = fmaf(o4.w, w3.z, a.z); a.w = fmaf(o4.w, w3.w, a.w);
                pacc[r] = a;
            }
        }
    }
    // store with inverse roll (+3,+3)
    const int b = bx >> 8;
#pragma unroll
    for (int r = 0; r < 7; r++) {
        int nn = rowbase + (r << 3);
        if (nn < NTOK) {
            int ph = nn / 7, pw = nn - (nn / 7) * 7;
            int ho = wi * 7 + ph + 3; if (ho >= IMG) ho -= IMG;
            int wo = wj * 7 + pw + 3; if (wo >= IMG) wo -= IMG;
            *(float4*)(out + ((size_t)((b * IMG + ho) * IMG + wo)) * CDIM + (e4 << 2)) = pacc[r];
        }
    }
}

extern "C" void kernel_launch(void* const* d_in, const int* in_sizes, int n_in,
                              void* d_out, int out_size, void* d_ws, size_t ws_size,
                              hipStream_t stream)
{
    const float* x         = (const float*)d_in[0];
    const float* w_qkv     = (const float*)d_in[1];
    const float* b_qkv     = (const float*)d_in[2];
    const float* w_proj    = (const float*)d_in[3];
    const float* b_proj    = (const float*)d_in[4];
    const float* log_sigma = (const float*)d_in[5];
    const float* bias_tab  = (const float*)d_in[6];
    float* out = (float*)d_out;
    float* qkv = (float*)d_ws;   // 200704*384 floats = 308 MB (win-gathered rows [win*49+tok][384])

    qkv_gemm_kernel<<<4704, 256, 0, stream>>>(x, w_qkv, b_qkv, qkv);
    attn_kernel<<<4096, 256, 0, stream>>>(qkv, w_proj, b_proj, log_sigma, bias_tab, out);
}

// Round 7
// 650.237 us; speedup vs baseline: 1.0769x; 1.0769x over previous
//
#include <hip/hip_runtime.h>
#include <math.h>
#include <stdint.h>

#define IMG 112
#define CDIM 128
#define NTOK 49

// async global->LDS, 16B per lane. Dest must be wave-uniform base (HW adds lane*16).
__device__ __forceinline__ void glds16(const float* g, float* l) {
    __builtin_amdgcn_global_load_lds(
        (const __attribute__((address_space(1))) uint32_t*)g,
        (__attribute__((address_space(3))) uint32_t*)l, 16, 0, 0);
}

// ================= K1: qkv = roll(x,-3,-3) @ w_qkv + b_qkv =================
// 128x128 tile, 256 threads, 8x8 micro (2x2 groups of 4x4 at offsets {0,64}).
// 2D grid (PROVEN: 1D jc-fast decode lands the 3 tensor-blocks on different
// XCDs -> no L2 sharing, +78MB write; reverted round 6).
// At[32][133]: bank = (5*(c4+j)+r)%32 covers all banks 2x -> 0 conflicts
// (PROVEN round 6: 7.2e6 -> 0).
// B staged via global_load_lds width-16 (no VGPR round-trip, no ds_write):
// Bs[32][128] un-padded -- glds dest is linear; B reads are within-row so
// pad is unnecessary (2-way max = free).
// Output layout: qkv[((b*16+wi)*16+wj)*49 + ph*7+pw][0:384], q/k pre-scaled.
__global__ __launch_bounds__(256, 4) void qkv_gemm_kernel(
    const float* __restrict__ x, const float* __restrict__ w,
    const float* __restrict__ bqkv, float* __restrict__ qkv)
{
    __shared__ float At[32][133];   // At[k][r] (A transposed)
    __shared__ float Bs[32][128];   // Bs[k][j], linear for glds
    const int tid = threadIdx.x;
    const int m0 = blockIdx.x << 7;
    const int j0 = blockIdx.y << 7;
    const int tm = tid >> 4, tn = tid & 15;
    const float fscale = (j0 < 256) ? 0.17677669529663687f : 1.0f;

    // hoisted A-load offsets: 4 ints only (no pointer arrays -> no spill)
    const int c4A = (tid & 7) << 2;
    const int r0 = tid >> 3;               // 0..31
    int aoff[4];
#pragma unroll
    for (int i = 0; i < 4; i++) {
        int r = r0 + (i << 5);
        int m = m0 + r;
        int b = m / (IMG * IMG);
        int rem = m - b * (IMG * IMG);
        int hh = rem / IMG;
        int ww_ = rem - hh * IMG;
        int hs = hh + 3; if (hs >= IMG) hs -= IMG;   // roll(-3) fold
        int ws = ww_ + 3; if (ws >= IMG) ws -= IMG;
        aoff[i] = ((b * IMG + hs) * IMG + ws) * CDIM + c4A;
    }
    // hoisted B-glds addressing: wave w, lane l -> row 2w+(l>=32), col (l&31)*4
    const int wv = tid >> 6;
    const int lane = tid & 63;
    const int brow0 = (wv << 1) + (lane >> 5);      // row within 8-row group
    const float* bsrc = w + (size_t)brow0 * 384 + j0 + ((lane & 31) << 2);
    float* bdst = &Bs[wv << 1][0];                  // wave-uniform dest base

    float acc[8][8];
#pragma unroll
    for (int i = 0; i < 8; i++)
#pragma unroll
        for (int j = 0; j < 8; j++) acc[i][j] = 0.0f;

    for (int kc = 0; kc < 4; kc++) {
        if (kc) __syncthreads();
        // B chunk: 32 k x 128 j via async glds (issue first, in flight during A)
#pragma unroll
        for (int i = 0; i < 4; i++)
            glds16(bsrc + (size_t)((kc << 5) + (i << 3)) * 384, bdst + (i << 3) * 128);
        // A chunk: 128 rows x 32 k, register round-trip transposed store
#pragma unroll
        for (int i = 0; i < 4; i++) {
            float4 v = *(const float4*)(x + aoff[i] + (kc << 5));
            int r = r0 + (i << 5);
            At[c4A + 0][r] = v.x;
            At[c4A + 1][r] = v.y;
            At[c4A + 2][r] = v.z;
            At[c4A + 3][r] = v.w;
        }
        __syncthreads();   // drains vmcnt (glds) + lgkm -> Bs and At ready
#pragma unroll
        for (int c = 0; c < 32; c++) {
            float4 a0 = *(const float4*)(&At[c][tm << 2]);
            float4 a1 = *(const float4*)(&At[c][64 + (tm << 2)]);
            float4 b0 = *(const float4*)(&Bs[c][tn << 2]);
            float4 b1 = *(const float4*)(&Bs[c][64 + (tn << 2)]);
            float av[8] = {a0.x, a0.y, a0.z, a0.w, a1.x, a1.y, a1.z, a1.w};
            float bv[8] = {b0.x, b0.y, b0.z, b0.w, b1.x, b1.y, b1.z, b1.w};
#pragma unroll
            for (int ii = 0; ii < 8; ii++)
#pragma unroll
                for (int jj = 0; jj < 8; jj++) acc[ii][jj] = fmaf(av[ii], bv[jj], acc[ii][jj]);
        }
    }
    const int jb0 = j0 + (tn << 2);
    float4 bq0 = *(const float4*)(bqkv + jb0);
    float4 bq1 = *(const float4*)(bqkv + jb0 + 64);
#pragma unroll
    for (int ih = 0; ih < 2; ih++) {
#pragma unroll
        for (int ii = 0; ii < 4; ii++) {
            int r = (ih << 6) + (tm << 2) + ii;
            int m = m0 + r;
            int b = m / (IMG * IMG);
            int rem = m - b * (IMG * IMG);
            int hh = rem / IMG;
            int ww_ = rem - hh * IMG;
            int wi = hh / 7, ph = hh - wi * 7;
            int wj = ww_ / 7, pw = ww_ - wj * 7;
            size_t mp = (size_t)(((b * 16 + wi) * 16 + wj) * 49 + ph * 7 + pw);
            int ai = (ih << 2) + ii;
            float4 o0, o1;
            o0.x = (acc[ai][0] + bq0.x) * fscale;
            o0.y = (acc[ai][1] + bq0.y) * fscale;
            o0.z = (acc[ai][2] + bq0.z) * fscale;
            o0.w = (acc[ai][3] + bq0.w) * fscale;
            o1.x = (acc[ai][4] + bq1.x) * fscale;
            o1.y = (acc[ai][5] + bq1.y) * fscale;
            o1.z = (acc[ai][6] + bq1.z) * fscale;
            o1.w = (acc[ai][7] + bq1.w) * fscale;
            *(float4*)(qkv + mp * 384 + jb0) = o0;
            *(float4*)(qkv + mp * 384 + jb0 + 64) = o1;
        }
    }
}

// ================= K2: wave-per-head window attention + fused proj =================
// (unchanged — proven round-5 variant)
#define KVSLAB 3136
#define OFF_BT 12544
#define SM_FLOATS 13220

__global__ __launch_bounds__(256, 3) void attn_kernel(
    const float* __restrict__ qkv, const float* __restrict__ wproj,
    const float* __restrict__ bproj, const float* __restrict__ lsig,
    const float* __restrict__ btab, float* __restrict__ out)
{
    __shared__ float sm[SM_FLOATS];
    const int tid = threadIdx.x;
    const int lane = tid & 63;
    const int h = tid >> 6;
    const int bx = blockIdx.x;
    const int wi = (bx >> 4) & 15;
    const int wj = bx & 15;

    float* kh  = sm + h * KVSLAB;
    float* vh  = kh + 1568;
    float* bts = sm + OFF_BT;
    float* osb = sm;            // proj-phase alias

    for (int i = tid; i < 676; i += 256) bts[i] = btab[i];

    const bool fi = (wi == 15), fj = (wj == 15);
    float4 q[8];
    float qsq = 0.0f, ks = 0.0f;
    int pbit = 0, qbit = 0, rbase = 0;

    const float* blkbase = qkv + (size_t)bx * (49 * 384);

    if (lane < NTOK) {
        int nh_ = lane / 7, nw_ = lane - (lane / 7) * 7;
        rbase = (nh_ * 13 + nw_) * 4 + h;
        pbit = (nh_ < 4) ? 1 : 0;
        qbit = (nw_ < 4) ? 1 : 0;
        const float* rowp = blkbase + lane * 384 + h * 32;
#pragma unroll
        for (int d4 = 0; d4 < 8; d4++) {
            float4 qv = *(const float4*)(rowp + (d4 << 2));
            q[d4] = qv;
            qsq = fmaf(qv.x, qv.x, qsq); qsq = fmaf(qv.y, qv.y, qsq);
            qsq = fmaf(qv.z, qv.z, qsq); qsq = fmaf(qv.w, qv.w, qsq);
            float4 kv = *(const float4*)(rowp + 128 + (d4 << 2));
            ks = fmaf(kv.x, kv.x, ks); ks = fmaf(kv.y, kv.y, ks);
            ks = fmaf(kv.z, kv.z, ks); ks = fmaf(kv.w, kv.w, ks);
            *(float4*)(kh + lane * 32 + ((d4 ^ (lane & 7)) << 2)) = kv;
            float4 vv = *(const float4*)(rowp + 256 + (d4 << 2));
            *(float4*)(vh + lane * 32 + ((d4 ^ (lane & 7)) << 2)) = vv;
        }
    }
    __syncthreads();

    float4 o[8];
#pragma unroll
    for (int d4 = 0; d4 < 8; d4++) { o[d4].x = 0.f; o[d4].y = 0.f; o[d4].z = 0.f; o[d4].w = 0.f; }
    float inv = 0.0f;

    if (lane < NTOK) {
        const float coef = -0.5f * __expf(-2.0f * lsig[h]);
        float s[49];
#pragma unroll
        for (int m = 0; m < 49; m++) {
            const int mh = m / 7, mw = m - (m / 7) * 7;
            float qk = 0.0f;
#pragma unroll
            for (int d4 = 0; d4 < 8; d4++) {
                float4 k4 = *(const float4*)(kh + m * 32 + ((d4 ^ (m & 7)) << 2));
                qk = fmaf(q[d4].x, k4.x, qk); qk = fmaf(q[d4].y, k4.y, qk);
                qk = fmaf(q[d4].z, k4.z, qk); qk = fmaf(q[d4].w, k4.w, qk);
            }
            float ksm = __shfl(ks, m, 64);
            float dist = fmaxf(qsq + ksm - 2.0f * qk, 1e-12f);
            float bias = bts[rbase + ((6 - mh) * 13 + (6 - mw)) * 4];
            int msk = (fi ? (pbit ^ ((mh < 4) ? 1 : 0)) : 0) | (fj ? (qbit ^ ((mw < 4) ? 1 : 0)) : 0);
            s[m] = fmaf(coef, dist, msk ? bias - 100.0f : bias);
        }
        // register-resident softmax
        float mx = s[0];
#pragma unroll
        for (int m = 1; m < 49; m++) mx = fmaxf(mx, s[m]);
        float sum = 0.0f;
#pragma unroll
        for (int m = 0; m < 49; m++) { float e = __expf(s[m] - mx); s[m] = e; sum += e; }
        inv = 1.0f / sum;
#pragma unroll
        for (int m = 0; m < 49; m++) {
            const float p = s[m];
#pragma unroll
            for (int d4 = 0; d4 < 8; d4++) {
                float4 v4 = *(const float4*)(vh + m * 32 + ((d4 ^ (m & 7)) << 2));
                o[d4].x = fmaf(p, v4.x, o[d4].x);
                o[d4].y = fmaf(p, v4.y, o[d4].y);
                o[d4].z = fmaf(p, v4.z, o[d4].z);
                o[d4].w = fmaf(p, v4.w, o[d4].w);
            }
        }
    }
    __syncthreads();   // all waves done reading k/v -> safe to alias

    if (lane < NTOK) {
#pragma unroll
        for (int d4 = 0; d4 < 8; d4++) {
            float4 ov;
            ov.x = o[d4].x * inv; ov.y = o[d4].y * inv;
            ov.z = o[d4].z * inv; ov.w = o[d4].w * inv;
            int gg = (h << 3) + d4;
            *(float4*)(osb + lane * 128 + ((gg ^ (lane & 7)) << 2)) = ov;
        }
    }
    __syncthreads();

    // ---- fused proj: out_tile(49x128) @ w_proj(128x128) + b_proj ----
    const int e4 = tid & 31;
    const int rowbase = tid >> 5;
    float4 bv = *(const float4*)(bproj + (e4 << 2));
    float4 pacc[7];
#pragma unroll
    for (int r = 0; r < 7; r++) pacc[r] = bv;

#pragma unroll 4
    for (int c = 0; c < 32; c++) {
        const float* wr = wproj + ((c << 2) * 128) + (e4 << 2);
        float4 w0 = *(const float4*)(wr);
        float4 w1 = *(const float4*)(wr + 128);
        float4 w2 = *(const float4*)(wr + 256);
        float4 w3 = *(const float4*)(wr + 384);
#pragma unroll
        for (int r = 0; r < 7; r++) {
            int nn = rowbase + (r << 3);
            if (nn < NTOK) {
                float4 o4 = *(const float4*)(osb + nn * 128 + ((c ^ (nn & 7)) << 2));
                float4 a = pacc[r];
                a.x = fmaf(o4.x, w0.x, a.x); a.y = fmaf(o4.x, w0.y, a.y);
                a.z = fmaf(o4.x, w0.z, a.z); a.w = fmaf(o4.x, w0.w, a.w);
                a.x = fmaf(o4.y, w1.x, a.x); a.y = fmaf(o4.y, w1.y, a.y);
                a.z = fmaf(o4.y, w1.z, a.z); a.w = fmaf(o4.y, w1.w, a.w);
                a.x = fmaf(o4.z, w2.x, a.x); a.y = fmaf(o4.z, w2.y, a.y);
                a.z = fmaf(o4.z, w2.z, a.z); a.w = fmaf(o4.z, w2.w, a.w);
                a.x = fmaf(o4.w, w3.x, a.x); a.y = fmaf(o4.w, w3.y, a.y);
                a.z = fmaf(o4.w, w3.z, a.z); a.w = fmaf(o4.w, w3.w, a.w);
                pacc[r] = a;
            }
        }
    }
    // store with inverse roll (+3,+3)
    const int b = bx >> 8;
#pragma unroll
    for (int r = 0; r < 7; r++) {
        int nn = rowbase + (r << 3);
        if (nn < NTOK) {
            int ph = nn / 7, pw = nn - (nn / 7) * 7;
            int ho = wi * 7 + ph + 3; if (ho >= IMG) ho -= IMG;
            int wo = wj * 7 + pw + 3; if (wo >= IMG) wo -= IMG;
            *(float4*)(out + ((size_t)((b * IMG + ho) * IMG + wo)) * CDIM + (e4 << 2)) = pacc[r];
        }
    }
}

extern "C" void kernel_launch(void* const* d_in, const int* in_sizes, int n_in,
                              void* d_out, int out_size, void* d_ws, size_t ws_size,
                              hipStream_t stream)
{
    const float* x         = (const float*)d_in[0];
    const float* w_qkv     = (const float*)d_in[1];
    const float* b_qkv     = (const float*)d_in[2];
    const float* w_proj    = (const float*)d_in[3];
    const float* b_proj    = (const float*)d_in[4];
    const float* log_sigma = (const float*)d_in[5];
    const float* bias_tab  = (const float*)d_in[6];
    float* out = (float*)d_out;
    float* qkv = (float*)d_ws;   // 200704*384 floats = 308 MB (win-gathered rows [win*49+tok][384])

    dim3 g1(200704 / 128, 3);
    qkv_gemm_kernel<<<g1, 256, 0, stream>>>(x, w_qkv, b_qkv, qkv);
    attn_kernel<<<4096, 256, 0, stream>>>(qkv, w_proj, b_proj, log_sigma, bias_tab, out);
}